// Round 2
// baseline (494.621 us; speedup 1.0000x reference)
//
#include <hip/hip_runtime.h>

typedef __attribute__((ext_vector_type(8))) short short8;
typedef __attribute__((ext_vector_type(4))) float f32x4;
typedef unsigned short u16;
typedef unsigned int u32;

#define NH 16

__device__ __forceinline__ u16 f2bf(float f) {
  union { float f; u32 u; } v; v.f = f;
  u32 r = (v.u + 0x7fffu + ((v.u >> 16) & 1u)) >> 16;
  return (u16)r;
}

// ---------- convert x + Wq,Wk,Wv,Wo (fp32) -> bf16 into ws ----------
__global__ __launch_bounds__(256) void k_convert(
    const float* __restrict__ x, const float* __restrict__ wq,
    const float* __restrict__ wk, const float* __restrict__ wv,
    const float* __restrict__ wo, u16* __restrict__ dst) {
  int i = blockIdx.x * 256 + threadIdx.x;
  size_t e = (size_t)i * 4;
  const float* s; size_t off;
  if (e < 8388608ull)       { s = x;  off = e; }
  else if (e < 9437184ull)  { s = wq; off = e - 8388608ull; }
  else if (e < 10485760ull) { s = wk; off = e - 9437184ull; }
  else if (e < 11534336ull) { s = wv; off = e - 10485760ull; }
  else                      { s = wo; off = e - 11534336ull; }
  float4 d = *(const float4*)(s + off);
  ushort4 o;
  o.x = f2bf(d.x); o.y = f2bf(d.y); o.z = f2bf(d.z); o.w = f2bf(d.w);
  *(ushort4*)(dst + e) = o;
}

// ---------- shared GEMM core: C[128x128] = A[128xK] * B[128xK]^T ----------
#define GEMM_CORE(Aptr, Bptr)                                                   \
  __shared__ u16 As[128 * 72];                                                  \
  __shared__ u16 Bs[128 * 72];                                                  \
  const int tid = threadIdx.x;                                                  \
  const int wave = tid >> 6, lane = tid & 63;                                   \
  const int wr = wave >> 1, wc = wave & 1;                                      \
  const int quad = lane >> 4, l16 = lane & 15;                                  \
  const int m0 = blockIdx.y * 128, n0 = blockIdx.x * 128;                       \
  f32x4 acc[4][4];                                                              \
  {                                                                             \
    f32x4 z = {0.f, 0.f, 0.f, 0.f};                                             \
    for (int a = 0; a < 4; ++a) for (int b2 = 0; b2 < 4; ++b2) acc[a][b2] = z;  \
  }                                                                             \
  for (int k0 = 0; k0 < 1024; k0 += 64) {                                       \
    _Pragma("unroll")                                                           \
    for (int i = 0; i < 4; ++i) {                                               \
      int c = i * 256 + tid;                                                    \
      int row = c >> 3, cc = c & 7;                                             \
      *(uint4*)(&As[row * 72 + cc * 8]) =                                       \
          *(const uint4*)(Aptr + (size_t)(m0 + row) * 1024 + k0 + cc * 8);      \
      *(uint4*)(&Bs[row * 72 + cc * 8]) =                                       \
          *(const uint4*)(Bptr + (size_t)(n0 + row) * 1024 + k0 + cc * 8);      \
    }                                                                           \
    __syncthreads();                                                            \
    _Pragma("unroll")                                                           \
    for (int ks = 0; ks < 2; ++ks) {                                            \
      short8 af[4], bfr[4];                                                     \
      _Pragma("unroll")                                                         \
      for (int t = 0; t < 4; ++t)                                               \
        af[t] = *(const short8*)(&As[(wr * 64 + t * 16 + l16) * 72 + ks * 32 + quad * 8]); \
      _Pragma("unroll")                                                         \
      for (int t = 0; t < 4; ++t)                                               \
        bfr[t] = *(const short8*)(&Bs[(wc * 64 + t * 16 + l16) * 72 + ks * 32 + quad * 8]); \
      _Pragma("unroll")                                                         \
      for (int mt = 0; mt < 4; ++mt) {                                          \
        _Pragma("unroll")                                                       \
        for (int nt = 0; nt < 4; ++nt)                                          \
          acc[mt][nt] = __builtin_amdgcn_mfma_f32_16x16x32_bf16(                \
              af[mt], bfr[nt], acc[mt][nt], 0, 0, 0);                           \
      }                                                                         \
    }                                                                           \
    __syncthreads();                                                            \
  }

// ---------- QKV projection: out scattered to [B,H,T,Dh] bf16 ----------
__global__ __launch_bounds__(256, 2) void k_gemm_qkv(
    const u16* __restrict__ A, const u16* __restrict__ W,
    const float* __restrict__ bq, const float* __restrict__ bk,
    const float* __restrict__ bv, u16* __restrict__ qkv) {
  const int z = blockIdx.z;
  const u16* Bw = W + (size_t)z * 1048576;
  const float* bias = (z == 0) ? bq : (z == 1) ? bk : bv;
  u16* out = qkv + (size_t)z * 8388608;
  GEMM_CORE(A, Bw)
  // q: fold 1/sqrt(64) AND log2(e) (attention uses exp2)
  const float scl = (z == 0) ? 0.125f * 1.44269504088896340736f : 1.0f;
  #pragma unroll
  for (int mt = 0; mt < 4; ++mt) {
    #pragma unroll
    for (int nt = 0; nt < 4; ++nt) {
      int n = n0 + wc * 64 + nt * 16 + l16;
      float bn = bias[n];
      int h = n >> 6, d = n & 63;
      #pragma unroll
      for (int r = 0; r < 4; ++r) {
        int m = m0 + wr * 64 + mt * 16 + quad * 4 + r;
        int b = m >> 11, t = m & 2047;
        float val = (acc[mt][nt][r] + bn) * scl;
        out[(((size_t)(b * NH + h) * 2048 + t) << 6) + d] = f2bf(val);
      }
    }
  }
}

// ---------- output projection: fp32 out [8192][1024] ----------
__global__ __launch_bounds__(256, 2) void k_gemm_out(
    const u16* __restrict__ A, const u16* __restrict__ Bw,
    const float* __restrict__ bias, float* __restrict__ out) {
  GEMM_CORE(A, Bw)
  #pragma unroll
  for (int mt = 0; mt < 4; ++mt) {
    #pragma unroll
    for (int nt = 0; nt < 4; ++nt) {
      int n = n0 + wc * 64 + nt * 16 + l16;
      float bn = bias[n];
      #pragma unroll
      for (int r = 0; r < 4; ++r) {
        int m = m0 + wr * 64 + mt * 16 + quad * 4 + r;
        out[(size_t)m * 1024 + n] = acc[mt][nt][r] + bn;
      }
    }
  }
}

// ---------- V transpose: [B,H,T,Dh] -> [B,H,Dh,T] bf16 ----------
__global__ __launch_bounds__(256) void k_vtrans(const u16* __restrict__ v,
                                                u16* __restrict__ vt) {
  int t0 = blockIdx.x * 64;
  int bh = blockIdx.y;
  const u16* vs = v + (size_t)bh * 2048 * 64;
  u16* vd = vt + (size_t)bh * 64 * 2048;
  int tid = threadIdx.x;
  #pragma unroll
  for (int it = 0; it < 2; ++it) {
    int c = it * 256 + tid;
    int d = c >> 3, tc = c & 7;
    union { u16 s[8]; uint4 q; } tmp;
    #pragma unroll
    for (int j = 0; j < 8; ++j)
      tmp.s[j] = vs[(size_t)(t0 + tc * 8 + j) * 64 + d];
    *(uint4*)(vd + (size_t)d * 2048 + t0 + tc * 8) = tmp.q;
  }
}

// ---------- flash attention (S^T orientation): per (bh, 64-row q tile) ----
// S^T = K*Q^T puts q on lanes, k on regs: softmax reductions are serial
// in-register + 2 shfl_xor; P exits in near-A-layout (b64 packed LDS writes).
__global__ __launch_bounds__(256, 2) void k_attn(
    const u16* __restrict__ q, const u16* __restrict__ k,
    const u16* __restrict__ vt, u16* __restrict__ y) {
  const int tid = threadIdx.x;
  const int wave = tid >> 6, lane = tid & 63;
  const int quad = lane >> 4, l16 = lane & 15;
  const int qt = blockIdx.x, bh = blockIdx.y;
  const int b = bh >> 4, h = bh & 15;

  __shared__ u16 Ks[64 * 72];
  __shared__ u16 Vs[64 * 72];           // [d][kidx]
  __shared__ u16 Ps[4 * 16 * 72];       // per-wave 16 q-rows x 64 k

  const u16* qb = q + ((size_t)bh * 2048 + qt * 64 + wave * 16 + l16) * 64;
  short8 qf0 = *(const short8*)(qb + quad * 8);
  short8 qf1 = *(const short8*)(qb + 32 + quad * 8);

  f32x4 o[4];
  { f32x4 z = {0.f,0.f,0.f,0.f}; for (int dt = 0; dt < 4; ++dt) o[dt] = z; }
  float m_i = -1e30f, l_i = 0.f;        // per-lane: row q = l16 (repl. quads)

  const u16* kbase = k + (size_t)bh * 2048 * 64;
  const u16* vbase = vt + (size_t)bh * 64 * 2048;
  const int r0 = tid >> 3, cc = tid & 7;

  uint4 kr[2], vr[2];
  #pragma unroll
  for (int i = 0; i < 2; ++i) {
    int row = i * 32 + r0;
    kr[i] = *(const uint4*)(kbase + (size_t)row * 64 + cc * 8);
    vr[i] = *(const uint4*)(vbase + (size_t)row * 2048 + cc * 8);
  }

  for (int kt = 0; kt <= qt; ++kt) {
    #pragma unroll
    for (int i = 0; i < 2; ++i) {
      int row = i * 32 + r0;
      *(uint4*)(&Ks[row * 72 + cc * 8]) = kr[i];
      *(uint4*)(&Vs[row * 72 + cc * 8]) = vr[i];
    }
    __syncthreads();

    if (kt < qt) {  // prefetch next tile into regs, overlapping compute
      const u16* kb = kbase + (size_t)(kt + 1) * 64 * 64;
      const u16* vb = vbase + (kt + 1) * 64;
      #pragma unroll
      for (int i = 0; i < 2; ++i) {
        int row = i * 32 + r0;
        kr[i] = *(const uint4*)(kb + (size_t)row * 64 + cc * 8);
        vr[i] = *(const uint4*)(vb + (size_t)row * 2048 + cc * 8);
      }
    }

    // S^T = K Q^T : lane l16 = q row, (nt,quad,r) = k column
    f32x4 st[4];
    #pragma unroll
    for (int nt = 0; nt < 4; ++nt) {
      short8 kf0 = *(const short8*)(&Ks[(nt * 16 + l16) * 72 + quad * 8]);
      short8 kf1 = *(const short8*)(&Ks[(nt * 16 + l16) * 72 + 32 + quad * 8]);
      f32x4 z4 = {0.f, 0.f, 0.f, 0.f};
      z4 = __builtin_amdgcn_mfma_f32_16x16x32_bf16(kf0, qf0, z4, 0, 0, 0);
      st[nt] = __builtin_amdgcn_mfma_f32_16x16x32_bf16(kf1, qf1, z4, 0, 0, 0);
    }

    if (kt == qt) {  // diagonal tile causal mask
      int q_loc = wave * 16 + l16;
      #pragma unroll
      for (int nt = 0; nt < 4; ++nt) {
        #pragma unroll
        for (int r = 0; r < 4; ++r) {
          int k_loc = nt * 16 + quad * 4 + r;
          if (k_loc > q_loc) st[nt][r] = -1e30f;
        }
      }
    }

    // online softmax (log2 domain; q pre-scaled by 0.125*log2e)
    float mx = -1e30f;
    #pragma unroll
    for (int nt = 0; nt < 4; ++nt)
      #pragma unroll
      for (int r = 0; r < 4; ++r) mx = fmaxf(mx, st[nt][r]);
    mx = fmaxf(mx, __shfl_xor(mx, 16, 64));
    mx = fmaxf(mx, __shfl_xor(mx, 32, 64));
    float mnew = fmaxf(m_i, mx);
    float alpha = exp2f(m_i - mnew);
    m_i = mnew;

    u16* pw = Ps + wave * 16 * 72;
    float sum = 0.f;
    #pragma unroll
    for (int nt = 0; nt < 4; ++nt) {
      union { u16 hx[4]; uint2 u; } pk;
      #pragma unroll
      for (int r = 0; r < 4; ++r) {
        float p = exp2f(st[nt][r] - mnew);
        sum += p;
        pk.hx[r] = f2bf(p);
      }
      *(uint2*)(&pw[l16 * 72 + nt * 16 + quad * 4]) = pk.u;  // b64 packed
    }
    sum += __shfl_xor(sum, 16, 64);
    sum += __shfl_xor(sum, 32, 64);
    l_i = l_i * alpha + sum;

    // rescale O (rows q on quad*4+r; alpha lives on lane l16=q -> broadcast)
    #pragma unroll
    for (int r = 0; r < 4; ++r) {
      float av = __shfl(alpha, quad * 4 + r, 16);
      #pragma unroll
      for (int dt = 0; dt < 4; ++dt) o[dt][r] *= av;
    }

    // O += P * V : A=P (m=q on l16), B=V^T (n=d on l16) -> D[q on quad/r][d on l16]
    #pragma unroll
    for (int ks = 0; ks < 2; ++ks) {
      short8 pf = *(const short8*)(pw + l16 * 72 + ks * 32 + quad * 8);
      #pragma unroll
      for (int dt = 0; dt < 4; ++dt) {
        short8 vf = *(const short8*)(&Vs[(dt * 16 + l16) * 72 + ks * 32 + quad * 8]);
        o[dt] = __builtin_amdgcn_mfma_f32_16x16x32_bf16(pf, vf, o[dt], 0, 0, 0);
      }
    }
    __syncthreads();
  }

  // epilogue: y[b][t][h][d] = O / l   (l lives on lane l16 = q -> broadcast)
  #pragma unroll
  for (int r = 0; r < 4; ++r) {
    float lv = __shfl(l_i, quad * 4 + r, 16);
    float inv = 1.0f / lv;
    int t = qt * 64 + wave * 16 + quad * 4 + r;
    #pragma unroll
    for (int dt = 0; dt < 4; ++dt) {
      int d = dt * 16 + l16;
      y[(((size_t)b * 2048 + t) * NH + h) * 64 + d] = f2bf(o[dt][r] * inv);
    }
  }
}

extern "C" void kernel_launch(void* const* d_in, const int* in_sizes, int n_in,
                              void* d_out, int out_size, void* d_ws, size_t ws_size,
                              hipStream_t stream) {
  const float* x  = (const float*)d_in[0];
  const float* Wq = (const float*)d_in[1];
  const float* bq = (const float*)d_in[2];
  const float* Wk = (const float*)d_in[3];
  const float* bk = (const float*)d_in[4];
  const float* Wv = (const float*)d_in[5];
  const float* bv = (const float*)d_in[6];
  const float* Wo = (const float*)d_in[7];
  const float* bo = (const float*)d_in[8];
  float* out = (float*)d_out;

  u16* ws  = (u16*)d_ws;
  u16* xb  = ws;                   // 8388608   x bf16 [8192][1024]
  u16* Wb  = ws + 8388608;         // 4x1048576 Wq|Wk|Wv|Wo bf16
  u16* qkv = ws + 12582912;        // 3x8388608 q|k|v [B,H,T,Dh] bf16
  u16* vt  = ws + 37748736;        // 8388608   v^T [B,H,Dh,T] bf16
  u16* y   = ws + 46137344;        // 8388608   attn out [B,T,H,Dh] bf16

  k_convert<<<dim3(12288), dim3(256), 0, stream>>>(x, Wq, Wk, Wv, Wo, ws);
  k_gemm_qkv<<<dim3(8, 64, 3), dim3(256), 0, stream>>>(xb, Wb, bq, bk, bv, qkv);
  k_vtrans<<<dim3(32, 64), dim3(256), 0, stream>>>(qkv + 2 * 8388608, vt);
  k_attn<<<dim3(32, 64), dim3(256), 0, stream>>>(qkv, qkv + 8388608, vt, y);
  k_gemm_out<<<dim3(8, 64), dim3(256), 0, stream>>>(y, Wb + 3 * 1048576, bo, out);
}

// Round 3
// 367.317 us; speedup vs baseline: 1.3466x; 1.3466x over previous
//
#include <hip/hip_runtime.h>

typedef __attribute__((ext_vector_type(8))) short short8;
typedef __attribute__((ext_vector_type(4))) float f32x4;
typedef unsigned short u16;
typedef unsigned int u32;

#define NH 16

#if __has_builtin(__builtin_amdgcn_exp2f)
#define EXP2(x) __builtin_amdgcn_exp2f(x)
#else
#define EXP2(x) exp2f(x)
#endif

__device__ __forceinline__ u32 f2bf(float f) {
  u32 u = __builtin_bit_cast(u32, f);
  return (u + 0x7fffu + ((u >> 16) & 1u)) >> 16;  // round-nearest-even bf16 bits
}

// ---------- convert x + Wq,Wk,Wv,Wo (fp32) -> bf16 into ws ----------
__global__ __launch_bounds__(256) void k_convert(
    const float* __restrict__ x, const float* __restrict__ wq,
    const float* __restrict__ wk, const float* __restrict__ wv,
    const float* __restrict__ wo, u16* __restrict__ dst) {
  int i = blockIdx.x * 256 + threadIdx.x;
  size_t e = (size_t)i * 4;
  const float* s; size_t off;
  if (e < 8388608ull)       { s = x;  off = e; }
  else if (e < 9437184ull)  { s = wq; off = e - 8388608ull; }
  else if (e < 10485760ull) { s = wk; off = e - 9437184ull; }
  else if (e < 11534336ull) { s = wv; off = e - 10485760ull; }
  else                      { s = wo; off = e - 11534336ull; }
  float4 d = *(const float4*)(s + off);
  ushort4 o;
  o.x = (u16)f2bf(d.x); o.y = (u16)f2bf(d.y);
  o.z = (u16)f2bf(d.z); o.w = (u16)f2bf(d.w);
  *(ushort4*)(dst + e) = o;
}

// ---------- shared GEMM core: C[128x128] = A[128xK] * B[128xK]^T ----------
#define GEMM_CORE(Aptr, Bptr)                                                   \
  __shared__ u16 As[128 * 72];                                                  \
  __shared__ u16 Bs[128 * 72];                                                  \
  const int tid = threadIdx.x;                                                  \
  const int wave = tid >> 6, lane = tid & 63;                                   \
  const int wr = wave >> 1, wc = wave & 1;                                      \
  const int quad = lane >> 4, l16 = lane & 15;                                  \
  const int m0 = blockIdx.y * 128, n0 = blockIdx.x * 128;                       \
  f32x4 acc[4][4];                                                              \
  {                                                                             \
    f32x4 z = {0.f, 0.f, 0.f, 0.f};                                             \
    for (int a = 0; a < 4; ++a) for (int b2 = 0; b2 < 4; ++b2) acc[a][b2] = z;  \
  }                                                                             \
  for (int k0 = 0; k0 < 1024; k0 += 64) {                                       \
    _Pragma("unroll")                                                           \
    for (int i = 0; i < 4; ++i) {                                               \
      int c = i * 256 + tid;                                                    \
      int row = c >> 3, cc = c & 7;                                             \
      *(uint4*)(&As[row * 72 + cc * 8]) =                                       \
          *(const uint4*)(Aptr + (size_t)(m0 + row) * 1024 + k0 + cc * 8);      \
      *(uint4*)(&Bs[row * 72 + cc * 8]) =                                       \
          *(const uint4*)(Bptr + (size_t)(n0 + row) * 1024 + k0 + cc * 8);      \
    }                                                                           \
    __syncthreads();                                                            \
    _Pragma("unroll")                                                           \
    for (int ks = 0; ks < 2; ++ks) {                                            \
      short8 af[4], bfr[4];                                                     \
      _Pragma("unroll")                                                         \
      for (int t = 0; t < 4; ++t)                                               \
        af[t] = *(const short8*)(&As[(wr * 64 + t * 16 + l16) * 72 + ks * 32 + quad * 8]); \
      _Pragma("unroll")                                                         \
      for (int t = 0; t < 4; ++t)                                               \
        bfr[t] = *(const short8*)(&Bs[(wc * 64 + t * 16 + l16) * 72 + ks * 32 + quad * 8]); \
      _Pragma("unroll")                                                         \
      for (int mt = 0; mt < 4; ++mt) {                                          \
        _Pragma("unroll")                                                       \
        for (int nt = 0; nt < 4; ++nt)                                          \
          acc[mt][nt] = __builtin_amdgcn_mfma_f32_16x16x32_bf16(                \
              af[mt], bfr[nt], acc[mt][nt], 0, 0, 0);                           \
      }                                                                         \
    }                                                                           \
    __syncthreads();                                                            \
  }

// ---------- QKV projection: out scattered to [B,H,T,Dh] bf16 ----------
__global__ __launch_bounds__(256, 2) void k_gemm_qkv(
    const u16* __restrict__ A, const u16* __restrict__ W,
    const float* __restrict__ bq, const float* __restrict__ bk,
    const float* __restrict__ bv, u16* __restrict__ qkv) {
  const int z = blockIdx.z;
  const u16* Bw = W + (size_t)z * 1048576;
  const float* bias = (z == 0) ? bq : (z == 1) ? bk : bv;
  u16* out = qkv + (size_t)z * 8388608;
  GEMM_CORE(A, Bw)
  // q: fold 1/sqrt(64) AND log2(e) (attention softmax runs in exp2 domain)
  const float scl = (z == 0) ? 0.125f * 1.44269504088896340736f : 1.0f;
  #pragma unroll
  for (int mt = 0; mt < 4; ++mt) {
    #pragma unroll
    for (int nt = 0; nt < 4; ++nt) {
      int n = n0 + wc * 64 + nt * 16 + l16;
      float bn = bias[n];
      int h = n >> 6, d = n & 63;
      #pragma unroll
      for (int r = 0; r < 4; ++r) {
        int m = m0 + wr * 64 + mt * 16 + quad * 4 + r;
        int b = m >> 11, t = m & 2047;
        float val = (acc[mt][nt][r] + bn) * scl;
        out[(((size_t)(b * NH + h) * 2048 + t) << 6) + d] = (u16)f2bf(val);
      }
    }
  }
}

// ---------- output projection: fp32 out [8192][1024] ----------
__global__ __launch_bounds__(256, 2) void k_gemm_out(
    const u16* __restrict__ A, const u16* __restrict__ Bw,
    const float* __restrict__ bias, float* __restrict__ out) {
  GEMM_CORE(A, Bw)
  #pragma unroll
  for (int mt = 0; mt < 4; ++mt) {
    #pragma unroll
    for (int nt = 0; nt < 4; ++nt) {
      int n = n0 + wc * 64 + nt * 16 + l16;
      float bn = bias[n];
      #pragma unroll
      for (int r = 0; r < 4; ++r) {
        int m = m0 + wr * 64 + mt * 16 + quad * 4 + r;
        out[(size_t)m * 1024 + n] = acc[mt][nt][r] + bn;
      }
    }
  }
}

// ---------- V transpose: [B,H,T,Dh] -> [B,H,Dh,T] bf16 ----------
__global__ __launch_bounds__(256) void k_vtrans(const u16* __restrict__ v,
                                                u16* __restrict__ vt) {
  int t0 = blockIdx.x * 64;
  int bh = blockIdx.y;
  const u16* vs = v + (size_t)bh * 2048 * 64;
  u16* vd = vt + (size_t)bh * 64 * 2048;
  int tid = threadIdx.x;
  #pragma unroll
  for (int it = 0; it < 2; ++it) {
    int c = it * 256 + tid;
    int d = c >> 3, tc = c & 7;
    u16 tmp[8];
    #pragma unroll
    for (int j = 0; j < 8; ++j)
      tmp[j] = vs[(size_t)(t0 + tc * 8 + j) * 64 + d];
    uint4 pk;
    pk.x = (u32)tmp[0] | ((u32)tmp[1] << 16);
    pk.y = (u32)tmp[2] | ((u32)tmp[3] << 16);
    pk.z = (u32)tmp[4] | ((u32)tmp[5] << 16);
    pk.w = (u32)tmp[6] | ((u32)tmp[7] << 16);
    *(uint4*)(vd + (size_t)d * 2048 + t0 + tc * 8) = pk;
  }
}

// ---------- flash attention, S^T orientation, paired q-tiles --------------
// Block bx handles q-tiles qtB=bx (short) and qtA=31-bx (long): constant 33
// tiles of work per block -> 1024 uniform blocks, shared K/V staging for the
// common kt prefix. S^T = K*Q^T puts q on lanes: softmax is serial-in-register
// + 2 shfl_xor; P packs to LDS via u32 bit-ops (NO unions -> no scratch).
#define ATTN_STEP(QF0, QF1, O, MI, LI, PW, DIAG)                               \
  {                                                                            \
    f32x4 st[4];                                                               \
    _Pragma("unroll")                                                          \
    for (int nt = 0; nt < 4; ++nt) {                                           \
      short8 kf0 = *(const short8*)(&Ks[(nt * 16 + l16) * 72 + quad * 8]);     \
      short8 kf1 = *(const short8*)(&Ks[(nt * 16 + l16) * 72 + 32 + quad * 8]);\
      f32x4 z4 = {0.f, 0.f, 0.f, 0.f};                                         \
      z4 = __builtin_amdgcn_mfma_f32_16x16x32_bf16(kf0, QF0, z4, 0, 0, 0);     \
      st[nt] = __builtin_amdgcn_mfma_f32_16x16x32_bf16(kf1, QF1, z4, 0, 0, 0); \
    }                                                                          \
    if (DIAG) {                                                                \
      int q_loc = wave * 16 + l16;                                             \
      _Pragma("unroll")                                                        \
      for (int nt = 0; nt < 4; ++nt) {                                         \
        _Pragma("unroll")                                                      \
        for (int r = 0; r < 4; ++r) {                                          \
          int k_loc = nt * 16 + quad * 4 + r;                                  \
          if (k_loc > q_loc) st[nt][r] = -1e30f;                               \
        }                                                                      \
      }                                                                        \
    }                                                                          \
    float mx = -1e30f;                                                         \
    _Pragma("unroll")                                                          \
    for (int nt = 0; nt < 4; ++nt)                                             \
      _Pragma("unroll")                                                        \
      for (int r = 0; r < 4; ++r) mx = fmaxf(mx, st[nt][r]);                   \
    mx = fmaxf(mx, __shfl_xor(mx, 16, 64));                                    \
    mx = fmaxf(mx, __shfl_xor(mx, 32, 64));                                    \
    float mnew = fmaxf(MI, mx);                                                \
    float alpha = EXP2(MI - mnew);                                             \
    MI = mnew;                                                                 \
    float sum = 0.f;                                                           \
    _Pragma("unroll")                                                          \
    for (int nt = 0; nt < 4; ++nt) {                                           \
      float p0 = EXP2(st[nt][0] - mnew);                                       \
      float p1 = EXP2(st[nt][1] - mnew);                                       \
      float p2 = EXP2(st[nt][2] - mnew);                                       \
      float p3 = EXP2(st[nt][3] - mnew);                                       \
      sum += p0 + p1 + p2 + p3;                                                \
      uint2 pk;                                                                \
      pk.x = f2bf(p0) | (f2bf(p1) << 16);                                      \
      pk.y = f2bf(p2) | (f2bf(p3) << 16);                                      \
      *(uint2*)(&PW[l16 * 72 + nt * 16 + quad * 4]) = pk;                      \
    }                                                                          \
    sum += __shfl_xor(sum, 16, 64);                                            \
    sum += __shfl_xor(sum, 32, 64);                                            \
    LI = LI * alpha + sum;                                                     \
    _Pragma("unroll")                                                          \
    for (int r = 0; r < 4; ++r) {                                              \
      float av = __shfl(alpha, quad * 4 + r, 16);                              \
      _Pragma("unroll")                                                        \
      for (int dt = 0; dt < 4; ++dt) O[dt][r] *= av;                           \
    }                                                                          \
    _Pragma("unroll")                                                          \
    for (int ks = 0; ks < 2; ++ks) {                                           \
      short8 pf = *(const short8*)(PW + l16 * 72 + ks * 32 + quad * 8);        \
      _Pragma("unroll")                                                        \
      for (int dt = 0; dt < 4; ++dt) {                                         \
        short8 vf = *(const short8*)(&Vs[(dt * 16 + l16) * 72 + ks * 32 + quad * 8]); \
        O[dt] = __builtin_amdgcn_mfma_f32_16x16x32_bf16(pf, vf, O[dt], 0, 0, 0); \
      }                                                                        \
    }                                                                          \
  }

#define ATTN_EPI(O, LI, QT)                                                    \
  _Pragma("unroll")                                                            \
  for (int r = 0; r < 4; ++r) {                                                \
    float lv = __shfl(LI, quad * 4 + r, 16);                                   \
    float inv = 1.0f / lv;                                                     \
    int t = (QT) * 64 + wave * 16 + quad * 4 + r;                              \
    _Pragma("unroll")                                                          \
    for (int dt = 0; dt < 4; ++dt) {                                           \
      int d = dt * 16 + l16;                                                   \
      y[(((size_t)b * 2048 + t) * NH + h) * 64 + d] = (u16)f2bf(O[dt][r] * inv); \
    }                                                                          \
  }

__global__ __launch_bounds__(256, 4) void k_attn(
    const u16* __restrict__ q, const u16* __restrict__ k,
    const u16* __restrict__ vt, u16* __restrict__ y) {
  const int tid = threadIdx.x;
  const int wave = tid >> 6, lane = tid & 63;
  const int quad = lane >> 4, l16 = lane & 15;
  const int bx = blockIdx.x, bh = blockIdx.y;
  const int qtB = bx, qtA = 31 - bx;   // qtB in 0..15, qtA in 16..31
  const int b = bh >> 4, h = bh & 15;

  __shared__ u16 Ks[64 * 72];
  __shared__ u16 Vs[64 * 72];           // [d][kidx]
  __shared__ u16 PsA[4 * 16 * 72];
  __shared__ u16 PsB[4 * 16 * 72];

  const u16* qbA = q + ((size_t)bh * 2048 + qtA * 64 + wave * 16 + l16) * 64;
  short8 qA0 = *(const short8*)(qbA + quad * 8);
  short8 qA1 = *(const short8*)(qbA + 32 + quad * 8);
  const u16* qbB = q + ((size_t)bh * 2048 + qtB * 64 + wave * 16 + l16) * 64;
  short8 qB0 = *(const short8*)(qbB + quad * 8);
  short8 qB1 = *(const short8*)(qbB + 32 + quad * 8);

  f32x4 oA[4], oB[4];
  {
    f32x4 z = {0.f, 0.f, 0.f, 0.f};
    #pragma unroll
    for (int dt = 0; dt < 4; ++dt) { oA[dt] = z; oB[dt] = z; }
  }
  float mA = -1e30f, lA = 0.f, mB = -1e30f, lB = 0.f;

  u16* pwA = PsA + wave * 16 * 72;
  u16* pwB = PsB + wave * 16 * 72;

  const u16* kbase = k + (size_t)bh * 2048 * 64;
  const u16* vbase = vt + (size_t)bh * 64 * 2048;
  const int r0 = tid >> 3, cc = tid & 7;

  uint4 kr[2], vr[2];
  #pragma unroll
  for (int i = 0; i < 2; ++i) {
    int row = i * 32 + r0;
    kr[i] = *(const uint4*)(kbase + (size_t)row * 64 + cc * 8);
    vr[i] = *(const uint4*)(vbase + (size_t)row * 2048 + cc * 8);
  }

  for (int kt = 0; kt <= qtA; ++kt) {
    #pragma unroll
    for (int i = 0; i < 2; ++i) {
      int row = i * 32 + r0;
      *(uint4*)(&Ks[row * 72 + cc * 8]) = kr[i];
      *(uint4*)(&Vs[row * 72 + cc * 8]) = vr[i];
    }
    __syncthreads();

    if (kt < qtA) {  // register-prefetch next K/V tile across the compute
      const u16* kb = kbase + (size_t)(kt + 1) * 64 * 64;
      const u16* vb = vbase + (kt + 1) * 64;
      #pragma unroll
      for (int i = 0; i < 2; ++i) {
        int row = i * 32 + r0;
        kr[i] = *(const uint4*)(kb + (size_t)row * 64 + cc * 8);
        vr[i] = *(const uint4*)(vb + (size_t)row * 2048 + cc * 8);
      }
    }

    ATTN_STEP(qA0, qA1, oA, mA, lA, pwA, (kt == qtA))
    if (kt <= qtB) {
      ATTN_STEP(qB0, qB1, oB, mB, lB, pwB, (kt == qtB))
    }
    __syncthreads();
  }

  ATTN_EPI(oA, lA, qtA)
  ATTN_EPI(oB, lB, qtB)
}

extern "C" void kernel_launch(void* const* d_in, const int* in_sizes, int n_in,
                              void* d_out, int out_size, void* d_ws, size_t ws_size,
                              hipStream_t stream) {
  const float* x  = (const float*)d_in[0];
  const float* Wq = (const float*)d_in[1];
  const float* bq = (const float*)d_in[2];
  const float* Wk = (const float*)d_in[3];
  const float* bk = (const float*)d_in[4];
  const float* Wv = (const float*)d_in[5];
  const float* bv = (const float*)d_in[6];
  const float* Wo = (const float*)d_in[7];
  const float* bo = (const float*)d_in[8];
  float* out = (float*)d_out;

  u16* ws  = (u16*)d_ws;
  u16* xb  = ws;                   // 8388608   x bf16 [8192][1024]
  u16* Wb  = ws + 8388608;         // 4x1048576 Wq|Wk|Wv|Wo bf16
  u16* qkv = ws + 12582912;        // 3x8388608 q|k|v [B,H,T,Dh] bf16
  u16* vt  = ws + 37748736;        // 8388608   v^T [B,H,Dh,T] bf16
  u16* y   = ws + 46137344;        // 8388608   attn out [B,T,H,Dh] bf16

  k_convert<<<dim3(12288), dim3(256), 0, stream>>>(x, Wq, Wk, Wv, Wo, ws);
  k_gemm_qkv<<<dim3(8, 64, 3), dim3(256), 0, stream>>>(xb, Wb, bq, bk, bv, qkv);
  k_vtrans<<<dim3(32, 64), dim3(256), 0, stream>>>(qkv + 2 * 8388608, vt);
  k_attn<<<dim3(16, 64), dim3(256), 0, stream>>>(qkv, qkv + 8388608, vt, y);
  k_gemm_out<<<dim3(8, 64), dim3(256), 0, stream>>>(y, Wb + 3 * 1048576, bo, out);
}